// Round 9
// baseline (844.789 us; speedup 1.0000x reference)
//
#include <hip/hip_runtime.h>
#include <cmath>

#define T_TOK 8192
#define HDIM 1024
#define IDIM 4096
#define NEXP 8

#define OFF_LOSS  8388608
#define OFF_USAGE 8388609
#define OFF_TOPE  8388617

typedef __attribute__((ext_vector_type(8))) short bf16x8;
typedef __attribute__((ext_vector_type(4))) float f32x4;
typedef unsigned short u16;
typedef unsigned int u32;

__device__ inline u16 f2bf(float f) {
  u32 u = __float_as_uint(f);
  u32 r = (u + 0x7FFFu + ((u >> 16) & 1u)) >> 16;
  return (u16)r;
}

__device__ inline void glds16(const void* g, void* l) {
  __builtin_amdgcn_global_load_lds(
      (const __attribute__((address_space(1))) u32*)g,
      (__attribute__((address_space(3))) u32*)l, 16, 0, 0);
}

// ---------------- convert x fp32 -> bf16 ----------------
__global__ __launch_bounds__(256)
void cvt_x(const float* __restrict__ x, u16* __restrict__ xb) {
  size_t i = ((size_t)blockIdx.x * 256 + threadIdx.x) * 8;
  float4 a = *(const float4*)(x + i);
  float4 b = *(const float4*)(x + i + 4);
  union { u16 s[8]; uint4 v; } u;
  u.s[0] = f2bf(a.x); u.s[1] = f2bf(a.y); u.s[2] = f2bf(a.z); u.s[3] = f2bf(a.w);
  u.s[4] = f2bf(b.x); u.s[5] = f2bf(b.y); u.s[6] = f2bf(b.z); u.s[7] = f2bf(b.w);
  *(uint4*)(xb + i) = u.v;
}

// ------- transpose+convert: src [E][R][C] f32 -> dst [E][C][R] bf16, 64x64 tile ------
__global__ __launch_bounds__(256)
void transpose_cvt64(const float* __restrict__ src, u16* __restrict__ dst, int R, int C) {
  __shared__ float tile[64][65];
  size_t eoff = (size_t)blockIdx.z * R * C;
  int r0 = blockIdx.y * 64, c0 = blockIdx.x * 64;
  const float* s = src + eoff;
  u16* d = dst + eoff;
  int tr = threadIdx.x >> 4;
  int tc = (threadIdx.x & 15) * 4;
#pragma unroll
  for (int it = 0; it < 4; it++) {
    int row = tr + it * 16;
    float4 v = *(const float4*)(s + (size_t)(r0 + row) * C + c0 + tc);
    tile[row][tc] = v.x; tile[row][tc + 1] = v.y;
    tile[row][tc + 2] = v.z; tile[row][tc + 3] = v.w;
  }
  __syncthreads();
  int wc = threadIdx.x >> 3;
  int wr = (threadIdx.x & 7) * 8;
#pragma unroll
  for (int it = 0; it < 2; it++) {
    int c = wc + it * 32;
    union { u16 s[8]; uint4 v; } u;
#pragma unroll
    for (int j = 0; j < 8; j++) u.s[j] = f2bf(tile[wr + j][c]);
    *(uint4*)(d + (size_t)(c0 + c) * R + r0 + wr) = u.v;
  }
}

// ---------------- router: f64 logits/softmax/top2, 4 tokens/block ----------------
__global__ __launch_bounds__(256)
void router_kernel(const float* __restrict__ x, const float* __restrict__ gw,
                   float* __restrict__ probs, int* __restrict__ counts,
                   int* __restrict__ tlist, float* __restrict__ wlist,
                   float* __restrict__ out) {
  int wid = threadIdx.x >> 6, lane = threadIdx.x & 63;
  int tok = blockIdx.x * 4 + wid;
  double acc[NEXP];
#pragma unroll
  for (int e = 0; e < NEXP; e++) acc[e] = 0.0;
  const float* xr = x + (size_t)tok * HDIM;
  for (int h = lane; h < HDIM; h += 64) {
    double xv = (double)xr[h];
    const float* g = gw + h * NEXP;
#pragma unroll
    for (int e = 0; e < NEXP; e++) acc[e] += xv * (double)g[e];
  }
#pragma unroll
  for (int off = 32; off > 0; off >>= 1) {
#pragma unroll
    for (int e = 0; e < NEXP; e++) acc[e] += __shfl_xor(acc[e], off);
  }
  if (lane == 0) {
    double m = acc[0];
#pragma unroll
    for (int e = 1; e < NEXP; e++) if (acc[e] > m) m = acc[e];
    double p[NEXP], ssum = 0.0;
#pragma unroll
    for (int e = 0; e < NEXP; e++) { p[e] = exp(acc[e] - m); ssum += p[e]; }
#pragma unroll
    for (int e = 0; e < NEXP; e++) p[e] /= ssum;
    int i1 = 0;
#pragma unroll
    for (int e = 1; e < NEXP; e++) if (p[e] > p[i1]) i1 = e;
    int i2 = (i1 == 0) ? 1 : 0;
#pragma unroll
    for (int e = 0; e < NEXP; e++) if (e != i1 && p[e] > p[i2]) i2 = e;
    double ps = p[i1] + p[i2];
#pragma unroll
    for (int e = 0; e < NEXP; e++) probs[(size_t)tok * NEXP + e] = (float)p[e];
    out[OFF_TOPE + tok] = (float)i1;
    int pos1 = atomicAdd(&counts[i1], 1);
    tlist[i1 * T_TOK + pos1] = tok;
    wlist[i1 * T_TOK + pos1] = (float)(p[i1] / ps);
    int pos2 = atomicAdd(&counts[i2], 1);
    tlist[i2 * T_TOK + pos2] = tok;
    wlist[i2 * T_TOK + pos2] = (float)(p[i2] / ps);
  }
}

__global__ void hbase_kernel(const int* __restrict__ counts, int* __restrict__ hbase) {
  if (threadIdx.x == 0 && blockIdx.x == 0) {
    int s = 0;
    for (int e = 0; e < NEXP; e++) { hbase[e] = s; s += counts[e]; }
    hbase[NEXP] = s;
  }
}

__global__ __launch_bounds__(256)
void usage_kernel(const float* __restrict__ probs, float* __restrict__ out) {
  int e = blockIdx.x;
  float s = 0.f;
  for (int t = threadIdx.x; t < T_TOK; t += 256) s += probs[(size_t)t * NEXP + e];
#pragma unroll
  for (int off = 32; off > 0; off >>= 1) s += __shfl_xor(s, off);
  __shared__ float red[4];
  int lane = threadIdx.x & 63, wid = threadIdx.x >> 6;
  if (lane == 0) red[wid] = s;
  __syncthreads();
  if (threadIdx.x == 0)
    out[OFF_USAGE + e] = (red[0] + red[1] + red[2] + red[3]) / (float)T_TOK;
}

__global__ void loss_kernel(float* __restrict__ out) {
  if (threadIdx.x == 0 && blockIdx.x == 0) {
    float s = 0.f;
    for (int e = 0; e < NEXP; e++) { float u = out[OFF_USAGE + e]; s += u * u; }
    out[OFF_LOSS] = (float)NEXP * s;
  }
}

// ======== 256x256 BK=64 GEMMs, 512 thr (8 waves 2Mx4N), m201-cadence 4 phases ========
// LDS 128KB: 2 bufs x { A[2kk][256r][32k] | B[2kk][256r][32k] } (k-major kk-halves).
// Swizzle slot^((row>>1)&3) on global source AND ds_read (R8: 0 conflicts).
// Per K-tile T (buf c = T&1), phases (m201 order: reads FIRST, then barrier,
// lgkmcnt, MFMA, barrier -- read latency overlaps barrier stagger; setprio
// keeps MFMA-ing waves preferred so the stagger persists):
//  P_A: rd B(kk0)+A-lo(kk0); stage (T+1)k1; bar; lgkm0; 16 MFMA; bar
//  P_B: rd A-hi(kk0); bar; lgkm0; 16 MFMA; vmcnt(8); bar   <- gates Tk1 landed
//  P_C: rd B(kk1)+A-lo(kk1); stage (T+2)k0; bar; lgkm0; 16 MFMA; bar
//  P_D: rd A-hi(kk1); bar; lgkm0; 16 MFMA; vmcnt(8); bar   <- gates (T+1)k0 landed
// Prolog stages 0k0,0k1,1k0 then vmcnt(8)+bar (0k0 landed). Last tile gates 0.
// Overwrite edges: stage(T+1,k1) after T-1.P_D bar (retires c^1-kk1 readers);
// stage(T+2,k0) after T.P_B bar (retires c-kk0 readers). All verified per-wave
// vmcnt + barrier => all-waves landed.

#define STAGE(Ts, kk)                                                        \
  do {                                                                       \
    int cs_ = (Ts) & 1;                                                      \
    u32 kof_ = (u32)(Ts) * 64 + (kk) * 32;                                   \
    u16* Ld_ = lds + cs_ * 32768 + (kk) * 8192;                              \
    glds16(pa0 + kof_, Ld_ + t * 8);                                         \
    glds16(pa1 + kof_, Ld_ + 4096 + t * 8);                                  \
    glds16(pb0 + kof_, Ld_ + 16384 + t * 8);                                 \
    glds16(pb1 + kof_, Ld_ + 16384 + 4096 + t * 8);                          \
  } while (0)

#define RD_B(Lp)                                                             \
  _Pragma("unroll") for (int ni = 0; ni < 4; ni++) {                         \
    int rb_ = wc * 64 + ni * 16 + lrow;                                      \
    bf_[ni] = *(const bf16x8*)&(Lp)[16384 + rb_ * 32 +                       \
                                    ((lslot ^ ((rb_ >> 1) & 3)) * 8)];       \
  }

#define RD_ALO(Lp)                                                           \
  _Pragma("unroll") for (int mi = 0; mi < 4; mi++) {                         \
    int r_ = wr * 128 + mi * 16 + lrow;                                      \
    af_[mi] = *(const bf16x8*)&(Lp)[r_ * 32 + ((lslot ^ ((r_ >> 1) & 3)) * 8)];\
  }

#define RD_AHI(Lp)                                                           \
  _Pragma("unroll") for (int mi = 0; mi < 4; mi++) {                         \
    int r_ = wr * 128 + 64 + mi * 16 + lrow;                                 \
    af_[mi] = *(const bf16x8*)&(Lp)[r_ * 32 + ((lslot ^ ((r_ >> 1) & 3)) * 8)];\
  }

#define MFMA16(base)                                                         \
  __builtin_amdgcn_s_setprio(1);                                             \
  _Pragma("unroll") for (int mi = 0; mi < 4; mi++)                           \
  _Pragma("unroll") for (int ni = 0; ni < 4; ni++)                           \
    acc[(base) + mi][ni] = __builtin_amdgcn_mfma_f32_16x16x32_bf16(          \
        af_[mi], bf_[ni], acc[(base) + mi][ni], 0, 0, 0);                    \
  __builtin_amdgcn_s_setprio(0);

#define GEMM_KLOOP(nt)                                                       \
  STAGE(0, 0); STAGE(0, 1); STAGE(1, 0);                                     \
  asm volatile("s_waitcnt vmcnt(8)" ::: "memory");                           \
  __builtin_amdgcn_s_barrier();                                              \
  _Pragma("unroll 2") for (int T = 0; T < (nt); ++T) {                       \
    int c_ = T & 1;                                                          \
    const u16* L0_ = lds + c_ * 32768;                                       \
    const u16* L1_ = lds + c_ * 32768 + 8192;                                \
    bf16x8 bf_[4], af_[4];                                                   \
    /* P_A */                                                                \
    RD_B(L0_); RD_ALO(L0_);                                                  \
    if (T + 1 < (nt)) STAGE(T + 1, 1);                                       \
    __builtin_amdgcn_s_barrier();                                            \
    asm volatile("s_waitcnt lgkmcnt(0)" ::: "memory");                       \
    MFMA16(0);                                                               \
    __builtin_amdgcn_s_barrier();                                            \
    /* P_B */                                                                \
    RD_AHI(L0_);                                                             \
    __builtin_amdgcn_s_barrier();                                            \
    asm volatile("s_waitcnt lgkmcnt(0)" ::: "memory");                       \
    MFMA16(4);                                                               \
    if (T == (nt) - 1) asm volatile("s_waitcnt vmcnt(0)" ::: "memory");      \
    else               asm volatile("s_waitcnt vmcnt(8)" ::: "memory");      \
    __builtin_amdgcn_s_barrier();                                            \
    /* P_C */                                                                \
    RD_B(L1_); RD_ALO(L1_);                                                  \
    if (T + 2 < (nt)) STAGE(T + 2, 0);                                       \
    __builtin_amdgcn_s_barrier();                                            \
    asm volatile("s_waitcnt lgkmcnt(0)" ::: "memory");                       \
    MFMA16(0);                                                               \
    __builtin_amdgcn_s_barrier();                                            \
    /* P_D */                                                                \
    RD_AHI(L1_);                                                             \
    __builtin_amdgcn_s_barrier();                                            \
    asm volatile("s_waitcnt lgkmcnt(0)" ::: "memory");                       \
    MFMA16(4);                                                               \
    if (T == (nt) - 1) asm volatile("s_waitcnt vmcnt(0)" ::: "memory");      \
    else               asm volatile("s_waitcnt vmcnt(8)" ::: "memory");      \
    __builtin_amdgcn_s_barrier();                                            \
  }

#define GEMM_COMMON                                                          \
  int t = threadIdx.x;                                                       \
  int lane = t & 63, wid = t >> 6;                                           \
  int lrow = lane & 15, lslot = lane >> 4;                                   \
  int wr = wid >> 2, wc = wid & 3;                                           \
  int rA = t >> 2;                                                           \
  int skA = (t & 3) ^ ((rA >> 1) & 3);                                       \
  f32x4 acc[8][4];                                                           \
  _Pragma("unroll") for (int i = 0; i < 8; i++)                              \
  _Pragma("unroll") for (int j = 0; j < 4; j++)                              \
      acc[i][j] = (f32x4){0.f, 0.f, 0.f, 0.f};

// ---------------- up GEMM: h = gelu(x[tok] @ up_w[e] + up_b[e]) ----------------
__global__ __launch_bounds__(512, 2)
void up_gemm(const u16* __restrict__ xb, const u16* __restrict__ wbt,
             const float* __restrict__ bias, const int* __restrict__ counts,
             const int* __restrict__ hbase, const int* __restrict__ tlist,
             u16* __restrict__ hout, int e_fixed) {
  const int NT = IDIM / 256;   // 16
  const int MT = T_TOK / 256;  // 32
  int q = gridDim.x >> 3;
  int orig = blockIdx.x;
  int wg = (orig & 7) * q + (orig >> 3);
  int e, tm, tn;
  if (e_fixed >= 0) { e = e_fixed; tm = wg / NT; tn = wg % NT; }
  else { e = wg / (MT * NT); int r = wg % (MT * NT); tm = r / NT; tn = r % NT; }
  int cnt = counts[e];
  int m0 = tm * 256;
  if (m0 >= cnt) return;
  int hb = (e_fixed >= 0) ? 0 : hbase[e];
  int n0 = tn * 256;

  __shared__ u16 lds[65536];  // 128 KB

  GEMM_COMMON

  const int* tl = tlist + e * T_TOK;
  int g0 = m0 + rA;       if (g0 > cnt - 1) g0 = cnt - 1;
  int g1 = m0 + 128 + rA; if (g1 > cnt - 1) g1 = cnt - 1;
  const u16* pa0 = xb + (size_t)tl[g0] * HDIM + skA * 8;
  const u16* pa1 = xb + (size_t)tl[g1] * HDIM + skA * 8;
  const u16* wb = wbt + (size_t)e * IDIM * HDIM;
  const u16* pb0 = wb + (size_t)(n0 + rA) * HDIM + skA * 8;
  const u16* pb1 = wb + (size_t)(n0 + 128 + rA) * HDIM + skA * 8;

  GEMM_KLOOP(HDIM / 64)   // 16 tiles

  float bv[4];
#pragma unroll
  for (int ni = 0; ni < 4; ni++)
    bv[ni] = bias[(size_t)e * IDIM + n0 + wc * 64 + ni * 16 + lrow];
  int r4 = lslot * 4;
#pragma unroll
  for (int mi = 0; mi < 8; mi++) {
    int rb = m0 + wr * 128 + mi * 16 + r4;
#pragma unroll
    for (int j = 0; j < 4; j++) {
      int row = rb + j;
      if (row < cnt) {
        u16* hp = hout + (size_t)(hb + row) * IDIM + n0 + wc * 64 + lrow;
#pragma unroll
        for (int ni = 0; ni < 4; ni++) {
          float v = acc[mi][ni][j] + bv[ni];
          float gl = 0.5f * v * (1.0f + erff(v * 0.70710678118654752f));
          hp[ni * 16] = f2bf(gl);
        }
      }
    }
  }
}

// ------- down GEMM, SPLIT-K=2: out[tok] += w * (h @ down_w[e] + down_b[e]) -------
__global__ __launch_bounds__(512, 2)
void down_gemm(const u16* __restrict__ h, const u16* __restrict__ wbt,
               const float* __restrict__ bias, const int* __restrict__ counts,
               const int* __restrict__ hbase, const int* __restrict__ tlist,
               const float* __restrict__ wlist, float* __restrict__ out, int e_fixed) {
  const int NT = HDIM / 256;   // 4
  const int MT = T_TOK / 256;  // 32
  const int KS = 2;
  int q = gridDim.x >> 3;
  int orig = blockIdx.x;
  int wg = (orig & 7) * q + (orig >> 3);
  int e, r;
  if (e_fixed >= 0) { e = e_fixed; r = wg; }
  else { e = wg / (MT * NT * KS); r = wg % (MT * NT * KS); }
  int tm = r / (NT * KS);
  int r2 = r % (NT * KS);
  int ks = r2 / NT;
  int tn = r2 % NT;
  int cnt = counts[e];
  int m0 = tm * 256;
  if (m0 >= cnt) return;
  int hb = (e_fixed >= 0) ? 0 : hbase[e];
  int n0 = tn * 256;
  int kbase = ks * (IDIM / KS);

  __shared__ u16 lds[65536];  // 128 KB

  GEMM_COMMON

  int g0 = m0 + rA;       if (g0 > cnt - 1) g0 = cnt - 1;
  int g1 = m0 + 128 + rA; if (g1 > cnt - 1) g1 = cnt - 1;
  const u16* pa0 = h + (size_t)(hb + g0) * IDIM + kbase + skA * 8;
  const u16* pa1 = h + (size_t)(hb + g1) * IDIM + kbase + skA * 8;
  const u16* wb = wbt + (size_t)e * HDIM * IDIM;
  const u16* pb0 = wb + (size_t)(n0 + rA) * IDIM + kbase + skA * 8;
  const u16* pb1 = wb + (size_t)(n0 + 128 + rA) * IDIM + kbase + skA * 8;

  GEMM_KLOOP((IDIM / KS) / 64)   // 32 tiles

  float bv[4];
#pragma unroll
  for (int ni = 0; ni < 4; ni++)
    bv[ni] = (ks == 0) ? bias[(size_t)e * HDIM + n0 + wc * 64 + ni * 16 + lrow] : 0.0f;
  int r4 = lslot * 4;
#pragma unroll
  for (int mi = 0; mi < 8; mi++) {
    int rb = m0 + wr * 128 + mi * 16 + r4;
#pragma unroll
    for (int j = 0; j < 4; j++) {
      int row = rb + j;
      if (row < cnt) {
        int tok = tlist[e * T_TOK + row];
        float w = wlist[e * T_TOK + row];
        float* op = out + (size_t)tok * HDIM + n0 + wc * 64 + lrow;
#pragma unroll
        for (int ni = 0; ni < 4; ni++)
          atomicAdd(&op[ni * 16], w * (acc[mi][ni][j] + bv[ni]));
      }
    }
  }
}

extern "C" void kernel_launch(void* const* d_in, const int* in_sizes, int n_in,
                              void* d_out, int out_size, void* d_ws, size_t ws_size,
                              hipStream_t stream) {
  const float* x   = (const float*)d_in[0];
  const float* gw  = (const float*)d_in[1];
  const float* upw = (const float*)d_in[2];
  const float* upb = (const float*)d_in[3];
  const float* dnw = (const float*)d_in[4];
  const float* dnb = (const float*)d_in[5];
  float* out = (float*)d_out;
  char* ws = (char*)d_ws;

  int*   counts = (int*)(ws + 0);
  int*   hbase  = (int*)(ws + 64);
  int*   tlist  = (int*)(ws + 256);
  float* wlist  = (float*)(ws + 256 + 262144);
  float* probs  = (float*)(ws + 256 + 2 * 262144);
  u16*   xb     = (u16*)(ws + 1048576);
  u16*   upbt   = (u16*)(ws + 1048576 + 16777216);
  u16*   dnbt   = (u16*)(ws + 1048576 + 16777216 + 67108864ull);
  u16*   hbuf   = (u16*)(ws + 1048576 + 16777216 + 2ull * 67108864ull);

  bool grouped = ws_size >= 286261248ull;

  hipMemsetAsync(counts, 0, 32, stream);
  hipMemsetAsync(d_out, 0, (size_t)out_size * 4, stream);

  cvt_x<<<4096, 256, 0, stream>>>(x, xb);
  transpose_cvt64<<<dim3(IDIM / 64, HDIM / 64, NEXP), 256, 0, stream>>>(upw, upbt, HDIM, IDIM);
  transpose_cvt64<<<dim3(HDIM / 64, IDIM / 64, NEXP), 256, 0, stream>>>(dnw, dnbt, IDIM, HDIM);
  router_kernel<<<T_TOK / 4, 256, 0, stream>>>(x, gw, probs, counts, tlist, wlist, out);
  hbase_kernel<<<1, 64, 0, stream>>>(counts, hbase);
  usage_kernel<<<NEXP, 256, 0, stream>>>(probs, out);
  loss_kernel<<<1, 64, 0, stream>>>(out);

  if (grouped) {
    up_gemm<<<NEXP * 32 * 16, 512, 0, stream>>>(xb, upbt, upb, counts, hbase, tlist, hbuf, -1);
    down_gemm<<<NEXP * 32 * 4 * 2, 512, 0, stream>>>(hbuf, dnbt, dnb, counts, hbase, tlist, wlist, out, -1);
  } else {
    for (int e = 0; e < NEXP; e++) {
      up_gemm<<<32 * 16, 512, 0, stream>>>(xb, upbt, upb, counts, hbase, tlist, hbuf, e);
      down_gemm<<<32 * 4 * 2, 512, 0, stream>>>(hbuf, dnbt, dnb, counts, hbase, tlist, wlist, out, e);
    }
  }
}

// Round 10
// 754.791 us; speedup vs baseline: 1.1192x; 1.1192x over previous
//
#include <hip/hip_runtime.h>
#include <cmath>

#define T_TOK 8192
#define HDIM 1024
#define IDIM 4096
#define NEXP 8

#define OFF_LOSS  8388608
#define OFF_USAGE 8388609
#define OFF_TOPE  8388617

typedef __attribute__((ext_vector_type(8))) short bf16x8;
typedef __attribute__((ext_vector_type(4))) float f32x4;
typedef unsigned short u16;
typedef unsigned int u32;

__device__ inline u16 f2bf(float f) {
  u32 u = __float_as_uint(f);
  u32 r = (u + 0x7FFFu + ((u >> 16) & 1u)) >> 16;
  return (u16)r;
}

// tanh-form gelu with fast exp: 0.5v(1+tanh(0.79788456(v+0.044715v^3)))
//  = v * sigmoid(1.59576912(v+0.044715v^3)); max |err| vs exact-erf gelu ~3e-3
//  (threshold 0.14, current absmax 0.0078 -> safe).
__device__ inline float gelu_fast(float v) {
  float u = v + 0.044715f * v * v * v;
  return v / (1.0f + __expf(-1.5957691216f * u));
}

__device__ inline void glds16(const void* g, void* l) {
  __builtin_amdgcn_global_load_lds(
      (const __attribute__((address_space(1))) u32*)g,
      (__attribute__((address_space(3))) u32*)l, 16, 0, 0);
}

// ------- transpose+convert: src [E][R][C] f32 -> dst [E][C][R] bf16, 64x64 tile ------
__global__ __launch_bounds__(256)
void transpose_cvt64(const float* __restrict__ src, u16* __restrict__ dst, int R, int C) {
  __shared__ float tile[64][65];
  size_t eoff = (size_t)blockIdx.z * R * C;
  int r0 = blockIdx.y * 64, c0 = blockIdx.x * 64;
  const float* s = src + eoff;
  u16* d = dst + eoff;
  int tr = threadIdx.x >> 4;
  int tc = (threadIdx.x & 15) * 4;
#pragma unroll
  for (int it = 0; it < 4; it++) {
    int row = tr + it * 16;
    float4 v = *(const float4*)(s + (size_t)(r0 + row) * C + c0 + tc);
    tile[row][tc] = v.x; tile[row][tc + 1] = v.y;
    tile[row][tc + 2] = v.z; tile[row][tc + 3] = v.w;
  }
  __syncthreads();
  int wc = threadIdx.x >> 3;
  int wr = (threadIdx.x & 7) * 8;
#pragma unroll
  for (int it = 0; it < 2; it++) {
    int c = wc + it * 32;
    union { u16 s[8]; uint4 v; } u;
#pragma unroll
    for (int j = 0; j < 8; j++) u.s[j] = f2bf(tile[wr + j][c]);
    *(uint4*)(d + (size_t)(c0 + c) * R + r0 + wr) = u.v;
  }
}

// ---- router: f64 logits/softmax/top2, 4 tokens/block; also emits xb (bf16 x) ----
__global__ __launch_bounds__(256)
void router_kernel(const float* __restrict__ x, const float* __restrict__ gw,
                   u16* __restrict__ xb,
                   float* __restrict__ probs, int* __restrict__ counts,
                   int* __restrict__ tlist, float* __restrict__ wlist,
                   float* __restrict__ out) {
  int wid = threadIdx.x >> 6, lane = threadIdx.x & 63;
  int tok = blockIdx.x * 4 + wid;
  double acc[NEXP];
#pragma unroll
  for (int e = 0; e < NEXP; e++) acc[e] = 0.0;
  const float* xr = x + (size_t)tok * HDIM;
  u16* xbr = xb + (size_t)tok * HDIM;
#pragma unroll
  for (int i = 0; i < 4; i++) {
    int h0 = (lane + i * 64) * 4;
    float4 v = *(const float4*)(xr + h0);
    union { u16 s[4]; uint2 u; } cv;
    cv.s[0] = f2bf(v.x); cv.s[1] = f2bf(v.y);
    cv.s[2] = f2bf(v.z); cv.s[3] = f2bf(v.w);
    *(uint2*)(xbr + h0) = cv.u;
    const float* g0 = gw + (size_t)h0 * NEXP;
#pragma unroll
    for (int e = 0; e < NEXP; e++)
      acc[e] += (double)v.x * (double)g0[e] +
                (double)v.y * (double)g0[NEXP + e] +
                (double)v.z * (double)g0[2 * NEXP + e] +
                (double)v.w * (double)g0[3 * NEXP + e];
  }
#pragma unroll
  for (int off = 32; off > 0; off >>= 1) {
#pragma unroll
    for (int e = 0; e < NEXP; e++) acc[e] += __shfl_xor(acc[e], off);
  }
  if (lane == 0) {
    double m = acc[0];
#pragma unroll
    for (int e = 1; e < NEXP; e++) if (acc[e] > m) m = acc[e];
    double p[NEXP], ssum = 0.0;
#pragma unroll
    for (int e = 0; e < NEXP; e++) { p[e] = exp(acc[e] - m); ssum += p[e]; }
#pragma unroll
    for (int e = 0; e < NEXP; e++) p[e] /= ssum;
    int i1 = 0;
#pragma unroll
    for (int e = 1; e < NEXP; e++) if (p[e] > p[i1]) i1 = e;
    int i2 = (i1 == 0) ? 1 : 0;
#pragma unroll
    for (int e = 0; e < NEXP; e++) if (e != i1 && p[e] > p[i2]) i2 = e;
    double ps = p[i1] + p[i2];
#pragma unroll
    for (int e = 0; e < NEXP; e++) probs[(size_t)tok * NEXP + e] = (float)p[e];
    out[OFF_TOPE + tok] = (float)i1;
    int pos1 = atomicAdd(&counts[i1], 1);
    tlist[i1 * T_TOK + pos1] = tok;
    wlist[i1 * T_TOK + pos1] = (float)(p[i1] / ps);
    int pos2 = atomicAdd(&counts[i2], 1);
    tlist[i2 * T_TOK + pos2] = tok;
    wlist[i2 * T_TOK + pos2] = (float)(p[i2] / ps);
  }
}

__global__ void hbase_kernel(const int* __restrict__ counts, int* __restrict__ hbase) {
  if (threadIdx.x == 0 && blockIdx.x == 0) {
    int s = 0;
    for (int e = 0; e < NEXP; e++) { hbase[e] = s; s += counts[e]; }
    hbase[NEXP] = s;
  }
}

__global__ __launch_bounds__(256)
void usage_kernel(const float* __restrict__ probs, float* __restrict__ out) {
  int e = blockIdx.x;
  float s = 0.f;
  for (int t = threadIdx.x; t < T_TOK; t += 256) s += probs[(size_t)t * NEXP + e];
#pragma unroll
  for (int off = 32; off > 0; off >>= 1) s += __shfl_xor(s, off);
  __shared__ float red[4];
  int lane = threadIdx.x & 63, wid = threadIdx.x >> 6;
  if (lane == 0) red[wid] = s;
  __syncthreads();
  if (threadIdx.x == 0)
    out[OFF_USAGE + e] = (red[0] + red[1] + red[2] + red[3]) / (float)T_TOK;
}

__global__ void loss_kernel(float* __restrict__ out) {
  if (threadIdx.x == 0 && blockIdx.x == 0) {
    float s = 0.f;
    for (int e = 0; e < NEXP; e++) { float u = out[OFF_USAGE + e]; s += u * u; }
    out[OFF_LOSS] = (float)NEXP * s;
  }
}

// ======== 128x128 BK=32 GEMMs, 256 threads (4 waves 2x2), dbuf 32KB, counted vmcnt ====
// R5 configuration (session best): per K-step  barrier -> stage(next) ->
// s_waitcnt vmcnt(4) -> compute(cur). XOR slot swizzle (slot^((row>>1)&3)) on
// source AND read: measured 0 bank conflicts.

// ---------------- up GEMM: h = gelu(x[tok] @ up_w[e] + up_b[e]) ----------------
__global__ __launch_bounds__(256, 3)
void up_gemm(const u16* __restrict__ xb, const u16* __restrict__ wbt,
             const float* __restrict__ bias, const int* __restrict__ counts,
             const int* __restrict__ hbase, const int* __restrict__ tlist,
             u16* __restrict__ hout, int e_fixed) {
  const int NT = IDIM / 128;   // 32
  const int MT = T_TOK / 128;  // 64
  int q = gridDim.x >> 3;
  int orig = blockIdx.x;
  int wg = (orig & 7) * q + (orig >> 3);   // XCD-chunked, bijective (nwg%8==0)
  int e, tm, tn;
  if (e_fixed >= 0) { e = e_fixed; tm = wg / NT; tn = wg % NT; }
  else { e = wg / (MT * NT); int r = wg % (MT * NT); tm = r / NT; tn = r % NT; }
  int cnt = counts[e];
  int m0 = tm * 128;
  if (m0 >= cnt) return;
  int hb = (e_fixed >= 0) ? 0 : hbase[e];
  int n0 = tn * 128;

  __shared__ u16 As[2 * 4096];
  __shared__ u16 Bs[2 * 4096];

  int t = threadIdx.x;
  int ra = t >> 2;
  int sw = (t & 3) ^ ((ra >> 1) & 3);

  const int* tl = tlist + e * T_TOK;
  int g0 = m0 + ra;      if (g0 > cnt - 1) g0 = cnt - 1;
  int g1 = m0 + ra + 64; if (g1 > cnt - 1) g1 = cnt - 1;
  const u16* pa0 = xb + (size_t)tl[g0] * HDIM + sw * 8;
  const u16* pa1 = xb + (size_t)tl[g1] * HDIM + sw * 8;
  const u16* wb = wbt + (size_t)e * IDIM * HDIM;
  const u16* pb0 = wb + (size_t)(n0 + ra) * HDIM + sw * 8;
  const u16* pb1 = wb + (size_t)(n0 + ra + 64) * HDIM + sw * 8;

  f32x4 acc[4][4];
#pragma unroll
  for (int i = 0; i < 4; i++)
#pragma unroll
    for (int j = 0; j < 4; j++) acc[i][j] = (f32x4){0.f, 0.f, 0.f, 0.f};

  int lane = t & 63, wid = t >> 6;
  int wr = (wid >> 1) * 64, wc = (wid & 1) * 64;
  int lrow = lane & 15, lslot = lane >> 4;

  auto stage = [&](int b, int k0) {
    u16* a = &As[b * 4096];
    u16* bb = &Bs[b * 4096];
    glds16(pa0 + k0, a + t * 8);
    glds16(pa1 + k0, a + 2048 + t * 8);
    glds16(pb0 + k0, bb + t * 8);
    glds16(pb1 + k0, bb + 2048 + t * 8);
  };
  auto compute = [&](int b) {
    const u16* A = &As[b * 4096];
    const u16* Bb = &Bs[b * 4096];
    bf16x8 af[4], bfv[4];
#pragma unroll
    for (int mi = 0; mi < 4; mi++) {
      int row = wr + mi * 16 + lrow;
      af[mi] = *(const bf16x8*)&A[row * 32 + ((lslot ^ ((row >> 1) & 3)) * 8)];
    }
#pragma unroll
    for (int ni = 0; ni < 4; ni++) {
      int row = wc + ni * 16 + lrow;
      bfv[ni] = *(const bf16x8*)&Bb[row * 32 + ((lslot ^ ((row >> 1) & 3)) * 8)];
    }
#pragma unroll
    for (int mi = 0; mi < 4; mi++)
#pragma unroll
      for (int ni = 0; ni < 4; ni++)
        acc[mi][ni] = __builtin_amdgcn_mfma_f32_16x16x32_bf16(af[mi], bfv[ni], acc[mi][ni], 0, 0, 0);
  };

  const int nk = HDIM / 32;  // 32
  stage(0, 0);
  for (int kt = 0; kt < nk; ++kt) {
    int b = kt & 1;
    __builtin_amdgcn_s_barrier();
    if (kt + 1 < nk) {
      stage(b ^ 1, (kt + 1) * 32);
      asm volatile("s_waitcnt vmcnt(4)" ::: "memory");
    } else {
      asm volatile("s_waitcnt vmcnt(0)" ::: "memory");
    }
    compute(b);
  }

  float bv[4];
#pragma unroll
  for (int ni = 0; ni < 4; ni++)
    bv[ni] = bias[(size_t)e * IDIM + n0 + wc + ni * 16 + lrow];
  int r4 = lslot * 4;
#pragma unroll
  for (int mi = 0; mi < 4; mi++) {
    int rb = m0 + wr + mi * 16 + r4;
#pragma unroll
    for (int j = 0; j < 4; j++) {
      int row = rb + j;
      if (row < cnt) {
        u16* hp = hout + (size_t)(hb + row) * IDIM + n0 + wc + lrow;
#pragma unroll
        for (int ni = 0; ni < 4; ni++) {
          float v = acc[mi][ni][j] + bv[ni];
          hp[ni * 16] = f2bf(gelu_fast(v));
        }
      }
    }
  }
}

// ------- down GEMM, SPLIT-K=2: out[tok] += w * (h @ down_w[e] + down_b[e]) -------
__global__ __launch_bounds__(256, 3)
void down_gemm(const u16* __restrict__ h, const u16* __restrict__ wbt,
               const float* __restrict__ bias, const int* __restrict__ counts,
               const int* __restrict__ hbase, const int* __restrict__ tlist,
               const float* __restrict__ wlist, float* __restrict__ out, int e_fixed) {
  const int NT = HDIM / 128;   // 8
  const int MT = T_TOK / 128;  // 64
  const int KS = 2;
  int q = gridDim.x >> 3;
  int orig = blockIdx.x;
  int wg = (orig & 7) * q + (orig >> 3);
  int e, r;
  if (e_fixed >= 0) { e = e_fixed; r = wg; }
  else { e = wg / (MT * NT * KS); r = wg % (MT * NT * KS); }
  int tm = r / (NT * KS);
  int r2 = r % (NT * KS);
  int ks = r2 / NT;
  int tn = r2 % NT;
  int cnt = counts[e];
  int m0 = tm * 128;
  if (m0 >= cnt) return;
  int hb = (e_fixed >= 0) ? 0 : hbase[e];
  int n0 = tn * 128;
  int kbase = ks * (IDIM / KS);   // 0 or 2048

  __shared__ u16 As[2 * 4096];
  __shared__ u16 Bs[2 * 4096];

  int t = threadIdx.x;
  int ra = t >> 2;
  int sw = (t & 3) ^ ((ra >> 1) & 3);

  int g0 = m0 + ra;      if (g0 > cnt - 1) g0 = cnt - 1;
  int g1 = m0 + ra + 64; if (g1 > cnt - 1) g1 = cnt - 1;
  const u16* pa0 = h + (size_t)(hb + g0) * IDIM + sw * 8;
  const u16* pa1 = h + (size_t)(hb + g1) * IDIM + sw * 8;
  const u16* wb = wbt + (size_t)e * HDIM * IDIM;
  const u16* pb0 = wb + (size_t)(n0 + ra) * IDIM + sw * 8;
  const u16* pb1 = wb + (size_t)(n0 + ra + 64) * IDIM + sw * 8;

  f32x4 acc[4][4];
#pragma unroll
  for (int i = 0; i < 4; i++)
#pragma unroll
    for (int j = 0; j < 4; j++) acc[i][j] = (f32x4){0.f, 0.f, 0.f, 0.f};

  int lane = t & 63, wid = t >> 6;
  int wr = (wid >> 1) * 64, wc = (wid & 1) * 64;
  int lrow = lane & 15, lslot = lane >> 4;

  auto stage = [&](int b, int k0) {
    u16* a = &As[b * 4096];
    u16* bb = &Bs[b * 4096];
    glds16(pa0 + k0, a + t * 8);
    glds16(pa1 + k0, a + 2048 + t * 8);
    glds16(pb0 + k0, bb + t * 8);
    glds16(pb1 + k0, bb + 2048 + t * 8);
  };
  auto compute = [&](int b) {
    const u16* A = &As[b * 4096];
    const u16* Bb = &Bs[b * 4096];
    bf16x8 af[4], bfv[4];
#pragma unroll
    for (int mi = 0; mi < 4; mi++) {
      int row = wr + mi * 16 + lrow;
      af[mi] = *(const bf16x8*)&A[row * 32 + ((lslot ^ ((row >> 1) & 3)) * 8)];
    }
#pragma unroll
    for (int ni = 0; ni < 4; ni++) {
      int row = wc + ni * 16 + lrow;
      bfv[ni] = *(const bf16x8*)&Bb[row * 32 + ((lslot ^ ((row >> 1) & 3)) * 8)];
    }
#pragma unroll
    for (int mi = 0; mi < 4; mi++)
#pragma unroll
      for (int ni = 0; ni < 4; ni++)
        acc[mi][ni] = __builtin_amdgcn_mfma_f32_16x16x32_bf16(af[mi], bfv[ni], acc[mi][ni], 0, 0, 0);
  };

  const int nk = (IDIM / KS) / 32;  // 64
  stage(0, kbase);
  for (int kt = 0; kt < nk; ++kt) {
    int b = kt & 1;
    __builtin_amdgcn_s_barrier();
    if (kt + 1 < nk) {
      stage(b ^ 1, kbase + (kt + 1) * 32);
      asm volatile("s_waitcnt vmcnt(4)" ::: "memory");
    } else {
      asm volatile("s_waitcnt vmcnt(0)" ::: "memory");
    }
    compute(b);
  }

  float bv[4];
#pragma unroll
  for (int ni = 0; ni < 4; ni++)
    bv[ni] = (ks == 0) ? bias[(size_t)e * HDIM + n0 + wc + ni * 16 + lrow] : 0.0f;
  int r4 = lslot * 4;
#pragma unroll
  for (int mi = 0; mi < 4; mi++) {
    int rb = m0 + wr + mi * 16 + r4;
#pragma unroll
    for (int j = 0; j < 4; j++) {
      int row = rb + j;
      if (row < cnt) {
        int tok = tlist[e * T_TOK + row];
        float w = wlist[e * T_TOK + row];
        float* op = out + (size_t)tok * HDIM + n0 + wc + lrow;
#pragma unroll
        for (int ni = 0; ni < 4; ni++)
          atomicAdd(&op[ni * 16], w * (acc[mi][ni][j] + bv[ni]));
      }
    }
  }
}

extern "C" void kernel_launch(void* const* d_in, const int* in_sizes, int n_in,
                              void* d_out, int out_size, void* d_ws, size_t ws_size,
                              hipStream_t stream) {
  const float* x   = (const float*)d_in[0];
  const float* gw  = (const float*)d_in[1];
  const float* upw = (const float*)d_in[2];
  const float* upb = (const float*)d_in[3];
  const float* dnw = (const float*)d_in[4];
  const float* dnb = (const float*)d_in[5];
  float* out = (float*)d_out;
  char* ws = (char*)d_ws;

  int*   counts = (int*)(ws + 0);
  int*   hbase  = (int*)(ws + 64);
  int*   tlist  = (int*)(ws + 256);
  float* wlist  = (float*)(ws + 256 + 262144);
  float* probs  = (float*)(ws + 256 + 2 * 262144);
  u16*   xb     = (u16*)(ws + 1048576);
  u16*   upbt   = (u16*)(ws + 1048576 + 16777216);
  u16*   dnbt   = (u16*)(ws + 1048576 + 16777216 + 67108864ull);
  u16*   hbuf   = (u16*)(ws + 1048576 + 16777216 + 2ull * 67108864ull);

  bool grouped = ws_size >= 286261248ull;

  hipMemsetAsync(counts, 0, 32, stream);
  hipMemsetAsync(d_out, 0, (size_t)out_size * 4, stream);

  transpose_cvt64<<<dim3(IDIM / 64, HDIM / 64, NEXP), 256, 0, stream>>>(upw, upbt, HDIM, IDIM);
  transpose_cvt64<<<dim3(HDIM / 64, IDIM / 64, NEXP), 256, 0, stream>>>(dnw, dnbt, IDIM, HDIM);
  router_kernel<<<T_TOK / 4, 256, 0, stream>>>(x, gw, xb, probs, counts, tlist, wlist, out);
  hbase_kernel<<<1, 64, 0, stream>>>(counts, hbase);
  usage_kernel<<<NEXP, 256, 0, stream>>>(probs, out);
  loss_kernel<<<1, 64, 0, stream>>>(out);

  if (grouped) {
    up_gemm<<<NEXP * 64 * 32, 256, 0, stream>>>(xb, upbt, upb, counts, hbase, tlist, hbuf, -1);
    down_gemm<<<NEXP * 64 * 8 * 2, 256, 0, stream>>>(hbuf, dnbt, dnb, counts, hbase, tlist, wlist, out, -1);
  } else {
    for (int e = 0; e < NEXP; e++) {
      up_gemm<<<64 * 32, 256, 0, stream>>>(xb, upbt, upb, counts, hbase, tlist, hbuf, e);
      down_gemm<<<64 * 8 * 2, 256, 0, stream>>>(hbuf, dnbt, dnb, counts, hbase, tlist, wlist, out, e);
    }
  }
}